// Round 3
// baseline (107.299 us; speedup 1.0000x reference)
//
#include <hip/hip_runtime.h>

#define BB 32
#define CC 3
#define HH 512
#define WW 512

typedef float f32x4 __attribute__((ext_vector_type(4)));

// 8192 blocks x 256 threads x 4 px/thread = 8.4M pixels.
// Swizzle: XCD k (= blockIdx.x % 8, default round-robin dispatch) gets the
// contiguous logical chunk [k*1024, (k+1)*1024) = 4 whole batch images, so
// row-reuse between adjacent pixel rows hits the same XCD's L2.
__global__ __launch_bounds__(256) void warp_kernel(const float* __restrict__ img,
                                                   const float* __restrict__ Htf,
                                                   float* __restrict__ out) {
    const int HW = HH * WW;

    int lb = (blockIdx.x & 7) * 1024 + (blockIdx.x >> 3);   // logical block, 0..8191
    int b = lb >> 8;                                        // 256 blocks per batch
    int base_pix = (lb & 255) * 1024 + threadIdx.x * 4;     // 4 consecutive px/thread

    // b uniform across block -> scalar loads
    const float* Hp = Htf + b * 9;
    float h00 = Hp[0], h01 = Hp[1], h02 = Hp[2];
    float h10 = Hp[3], h11 = Hp[4], h12 = Hp[5];
    float h20 = Hp[6], h21 = Hp[7], h22 = Hp[8];

    float wts[4][4];
    int   idx[4][4];

#pragma unroll
    for (int j = 0; j < 4; ++j) {
        int pix = base_pix + j;
        int h = pix >> 9;
        int w = pix & (WW - 1);

        float gx = -1.0f + 2.0f * (float)w / (float)(WW - 1);
        float gy = -1.0f + 2.0f * (float)h / (float)(HH - 1);

        float X = h00 * gx + h01 * gy + h02;
        float Y = h10 * gx + h11 * gy + h12;
        float T = h20 * gx + h21 * gy + h22;
        float rT = 1.0f / T;
        float x = X * rT;
        float y = Y * rT;

        float px = (x + 1.0f) * (WW * 0.5f);
        float py = (y + 1.0f) * (HH * 0.5f);

        float fx = floorf(px), fy = floorf(py);
        float x0 = fminf(fmaxf(fx,        0.0f), (float)(WW - 1));
        float x1 = fminf(fmaxf(fx + 1.0f, 0.0f), (float)(WW - 1));
        float y0 = fminf(fmaxf(fy,        0.0f), (float)(HH - 1));
        float y1 = fminf(fmaxf(fy + 1.0f, 0.0f), (float)(HH - 1));

        wts[j][0] = (x1 - px) * (y1 - py);   // wa
        wts[j][1] = (x1 - px) * (py - y0);   // wb
        wts[j][2] = (px - x0) * (y1 - py);   // wc
        wts[j][3] = (px - x0) * (py - y0);   // wd

        int ix0 = (int)x0, ix1 = (int)x1, iy0 = (int)y0, iy1 = (int)y1;
        idx[j][0] = iy0 * WW + ix0;
        idx[j][1] = iy1 * WW + ix0;
        idx[j][2] = iy0 * WW + ix1;
        idx[j][3] = iy1 * WW + ix1;
    }

    const float* ib   = img + (size_t)b * (CC * HW);
    float*       outb = out + (size_t)b * (CC * HW) + base_pix;

#pragma unroll
    for (int c = 0; c < CC; ++c) {
        const float* p = ib + c * HW;
        f32x4 v;
        v.x = wts[0][0]*p[idx[0][0]] + wts[0][1]*p[idx[0][1]] + wts[0][2]*p[idx[0][2]] + wts[0][3]*p[idx[0][3]];
        v.y = wts[1][0]*p[idx[1][0]] + wts[1][1]*p[idx[1][1]] + wts[1][2]*p[idx[1][2]] + wts[1][3]*p[idx[1][3]];
        v.z = wts[2][0]*p[idx[2][0]] + wts[2][1]*p[idx[2][1]] + wts[2][2]*p[idx[2][2]] + wts[2][3]*p[idx[2][3]];
        v.w = wts[3][0]*p[idx[3][0]] + wts[3][1]*p[idx[3][1]] + wts[3][2]*p[idx[3][2]] + wts[3][3]*p[idx[3][3]];
        __builtin_nontemporal_store(v, (f32x4*)(outb + c * HW));
    }
}

extern "C" void kernel_launch(void* const* d_in, const int* in_sizes, int n_in,
                              void* d_out, int out_size, void* d_ws, size_t ws_size,
                              hipStream_t stream) {
    const float* img = (const float*)d_in[0];
    const float* Htf = (const float*)d_in[1];
    float* out = (float*)d_out;

    int blocks = (BB * HH * WW) / (256 * 4);   // 8192
    warp_kernel<<<blocks, 256, 0, stream>>>(img, Htf, out);
}

// Round 4
// 53.623 us; speedup vs baseline: 2.0010x; 2.0010x over previous
//
#include <hip/hip_runtime.h>

#define BB 32
#define CC 3
#define HH 512
#define WW 512

// 32768 blocks x 256 threads x 1 px/thread.
// XCD swizzle: XCD k (= blockIdx.x % 8 under default round-robin dispatch)
// gets logical blocks [k*4096, (k+1)*4096) = 4 whole batch images, so
// row-reuse between adjacent pixel rows stays in that XCD's L2.
// Non-temporal stores keep the write-once output from evicting gather-reuse
// lines in L2 (round-3 evidence: FETCH 156->47 MB).
__global__ __launch_bounds__(256) void warp_kernel(const float* __restrict__ img,
                                                   const float* __restrict__ Htf,
                                                   float* __restrict__ out) {
    const int HW = HH * WW;

    int lb  = (blockIdx.x & 7) * 4096 + (blockIdx.x >> 3);  // logical block, 0..32767
    int b   = lb >> 10;                                     // 1024 blocks per batch
    int pix = (lb & 1023) * 256 + threadIdx.x;
    int h = pix >> 9;
    int w = pix & (WW - 1);

    // b uniform across block -> scalar loads
    const float* Hp = Htf + b * 9;
    float h00 = Hp[0], h01 = Hp[1], h02 = Hp[2];
    float h10 = Hp[3], h11 = Hp[4], h12 = Hp[5];
    float h20 = Hp[6], h21 = Hp[7], h22 = Hp[8];

    float gx = -1.0f + 2.0f * (float)w / (float)(WW - 1);
    float gy = -1.0f + 2.0f * (float)h / (float)(HH - 1);

    float X = h00 * gx + h01 * gy + h02;
    float Y = h10 * gx + h11 * gy + h12;
    float T = h20 * gx + h21 * gy + h22;
    float rT = 1.0f / T;
    float x = X * rT;
    float y = Y * rT;

    float px = (x + 1.0f) * (WW * 0.5f);
    float py = (y + 1.0f) * (HH * 0.5f);

    float fx = floorf(px), fy = floorf(py);
    float x0 = fminf(fmaxf(fx,        0.0f), (float)(WW - 1));
    float x1 = fminf(fmaxf(fx + 1.0f, 0.0f), (float)(WW - 1));
    float y0 = fminf(fmaxf(fy,        0.0f), (float)(HH - 1));
    float y1 = fminf(fmaxf(fy + 1.0f, 0.0f), (float)(HH - 1));

    float wa = (x1 - px) * (y1 - py);
    float wb = (x1 - px) * (py - y0);
    float wc = (px - x0) * (y1 - py);
    float wd = (px - x0) * (py - y0);

    int ix0 = (int)x0, ix1 = (int)x1, iy0 = (int)y0, iy1 = (int)y1;
    int oa = iy0 * WW + ix0;
    int ob = iy1 * WW + ix0;
    int oc = iy0 * WW + ix1;
    int od = iy1 * WW + ix1;

    const float* ib   = img + (size_t)b * (CC * HW);
    float*       outb = out + (size_t)b * (CC * HW) + pix;

#pragma unroll
    for (int c = 0; c < CC; ++c) {
        const float* p = ib + c * HW;
        float v = wa * p[oa] + wb * p[ob] + wc * p[oc] + wd * p[od];
        __builtin_nontemporal_store(v, outb + c * HW);
    }
}

extern "C" void kernel_launch(void* const* d_in, const int* in_sizes, int n_in,
                              void* d_out, int out_size, void* d_ws, size_t ws_size,
                              hipStream_t stream) {
    const float* img = (const float*)d_in[0];
    const float* Htf = (const float*)d_in[1];
    float* out = (float*)d_out;

    int blocks = (BB * HH * WW) / 256;   // 32768
    warp_kernel<<<blocks, 256, 0, stream>>>(img, Htf, out);
}

// Round 5
// 39.818 us; speedup vs baseline: 2.6947x; 1.3467x over previous
//
#include <hip/hip_runtime.h>

#define BB 32
#define CC 3
#define HH 512
#define WW 512

typedef float f32x2 __attribute__((ext_vector_type(2)));

// 32768 blocks x 256 threads x 1 px/thread.
// XCD swizzle (R3/R4 win): XCD k = blockIdx.x % 8 gets 4 whole batch images.
// NT stores (R4 win): write-once output doesn't evict gather-reuse lines.
// R5: horizontal corner pairs (x0,x0+1) fetched as one 8B load -> 6 gathers
// instead of 12. Clip semantics preserved via selects:
//   - clipx (ix1==ix0): C:=A, D:=B  (same value, reference weights still sum right)
//   - ix0==511 (implies clipx): load pair at 510, take the .y lane.
__global__ __launch_bounds__(256) void warp_kernel(const float* __restrict__ img,
                                                   const float* __restrict__ Htf,
                                                   float* __restrict__ out) {
    const int HW = HH * WW;

    int lb  = (blockIdx.x & 7) * 4096 + (blockIdx.x >> 3);  // logical block, 0..32767
    int b   = lb >> 10;                                     // 1024 blocks per batch
    int pix = (lb & 1023) * 256 + threadIdx.x;
    int h = pix >> 9;
    int w = pix & (WW - 1);

    // b uniform across block -> scalar loads
    const float* Hp = Htf + b * 9;
    float h00 = Hp[0], h01 = Hp[1], h02 = Hp[2];
    float h10 = Hp[3], h11 = Hp[4], h12 = Hp[5];
    float h20 = Hp[6], h21 = Hp[7], h22 = Hp[8];

    float gx = -1.0f + 2.0f * (float)w / (float)(WW - 1);
    float gy = -1.0f + 2.0f * (float)h / (float)(HH - 1);

    float X = h00 * gx + h01 * gy + h02;
    float Y = h10 * gx + h11 * gy + h12;
    float T = h20 * gx + h21 * gy + h22;
    float rT = 1.0f / T;
    float x = X * rT;
    float y = Y * rT;

    float px = (x + 1.0f) * (WW * 0.5f);
    float py = (y + 1.0f) * (HH * 0.5f);

    float fx = floorf(px), fy = floorf(py);
    float x0 = fminf(fmaxf(fx,        0.0f), (float)(WW - 1));
    float x1 = fminf(fmaxf(fx + 1.0f, 0.0f), (float)(WW - 1));
    float y0 = fminf(fmaxf(fy,        0.0f), (float)(HH - 1));
    float y1 = fminf(fmaxf(fy + 1.0f, 0.0f), (float)(HH - 1));

    float wa = (x1 - px) * (y1 - py);
    float wb = (x1 - px) * (py - y0);
    float wc = (px - x0) * (y1 - py);
    float wd = (px - x0) * (py - y0);

    int ix0 = (int)x0, ix1 = (int)x1, iy0 = (int)y0, iy1 = (int)y1;

    bool clipx = (ix1 == ix0);          // horizontal clip (left or right edge)
    bool hi    = (ix0 == WW - 1);       // right-most: shift pair base down one
    int  ix0m  = min(ix0, WW - 2);

    int offA = iy0 * WW + ix0m;         // y0-row pair base
    int offB = iy1 * WW + ix0m;         // y1-row pair base

    const float* ib   = img + (size_t)b * (CC * HW);
    float*       outb = out + (size_t)b * (CC * HW) + pix;

#pragma unroll
    for (int c = 0; c < CC; ++c) {
        const float* p = ib + c * HW;
        f32x2 fa, fb;
        __builtin_memcpy(&fa, p + offA, 8);
        __builtin_memcpy(&fb, p + offB, 8);
        float A  = hi ? fa.y : fa.x;
        float Cv = clipx ? A : fa.y;
        float Bv = hi ? fb.y : fb.x;
        float Dv = clipx ? Bv : fb.y;
        float v = wa * A + wb * Bv + wc * Cv + wd * Dv;
        __builtin_nontemporal_store(v, outb + c * HW);
    }
}

extern "C" void kernel_launch(void* const* d_in, const int* in_sizes, int n_in,
                              void* d_out, int out_size, void* d_ws, size_t ws_size,
                              hipStream_t stream) {
    const float* img = (const float*)d_in[0];
    const float* Htf = (const float*)d_in[1];
    float* out = (float*)d_out;

    int blocks = (BB * HH * WW) / 256;   // 32768
    warp_kernel<<<blocks, 256, 0, stream>>>(img, Htf, out);
}

// Round 6
// 39.254 us; speedup vs baseline: 2.7334x; 1.0144x over previous
//
#include <hip/hip_runtime.h>

#define BB 32
#define CC 3
#define HH 512
#define WW 512

typedef float f32x2 __attribute__((ext_vector_type(2)));

// 16384 blocks x 256 threads x 2 px/thread (vertically adjacent rows h, h+1).
// - XCD swizzle (R3/R4 win): XCD k = blockIdx.x % 8 owns 2048 logical blocks
//   = 4 whole batch images -> row reuse stays in one XCD's L2.
// - NT stores (R4 win): write-once output doesn't evict gather-reuse lines
//   (FETCH 156 -> 47 MB).
// - Paired 8B corner loads (R5 win): 2 gathers per row instead of 4.
// - R6: vertical pixel pair, all 12 row-loads issued before any FMA ->
//   2x memory-level parallelism per wave; consecutive lanes keep 1-px stride
//   (R3's horizontal multi-px broke that and regressed).
__global__ __launch_bounds__(256) void warp_kernel(const float* __restrict__ img,
                                                   const float* __restrict__ Htf,
                                                   float* __restrict__ out) {
    const int HW = HH * WW;

    int lb  = (blockIdx.x & 7) * 2048 + (blockIdx.x >> 3);  // logical block, 0..16383
    int b   = lb >> 9;                                      // 512 blocks per batch
    int rem = lb & 511;                                     // 256 row-pairs x 2 halves
    int h0  = (rem >> 1) * 2;
    int w   = (rem & 1) * 256 + threadIdx.x;

    // b uniform across block -> scalar loads
    const float* Hp = Htf + b * 9;
    float h00 = Hp[0], h01 = Hp[1], h02 = Hp[2];
    float h10 = Hp[3], h11 = Hp[4], h12 = Hp[5];
    float h20 = Hp[6], h21 = Hp[7], h22 = Hp[8];

    float gx = -1.0f + 2.0f * (float)w / (float)(WW - 1);

    float wts[2][4];
    int   offA[2], offB[2];
    bool  clipx[2], hi[2];

#pragma unroll
    for (int j = 0; j < 2; ++j) {
        int h = h0 + j;
        float gy = -1.0f + 2.0f * (float)h / (float)(HH - 1);

        float X = h00 * gx + h01 * gy + h02;
        float Y = h10 * gx + h11 * gy + h12;
        float T = h20 * gx + h21 * gy + h22;
        float rT = 1.0f / T;
        float x = X * rT;
        float y = Y * rT;

        float px = (x + 1.0f) * (WW * 0.5f);
        float py = (y + 1.0f) * (HH * 0.5f);

        float fxf = floorf(px), fyf = floorf(py);
        float x0 = fminf(fmaxf(fxf,        0.0f), (float)(WW - 1));
        float x1 = fminf(fmaxf(fxf + 1.0f, 0.0f), (float)(WW - 1));
        float y0 = fminf(fmaxf(fyf,        0.0f), (float)(HH - 1));
        float y1 = fminf(fmaxf(fyf + 1.0f, 0.0f), (float)(HH - 1));

        wts[j][0] = (x1 - px) * (y1 - py);   // wa
        wts[j][1] = (x1 - px) * (py - y0);   // wb
        wts[j][2] = (px - x0) * (y1 - py);   // wc
        wts[j][3] = (px - x0) * (py - y0);   // wd

        int ix0 = (int)x0, ix1 = (int)x1, iy0 = (int)y0, iy1 = (int)y1;
        clipx[j] = (ix1 == ix0);
        hi[j]    = (ix0 == WW - 1);
        int ix0m = min(ix0, WW - 2);
        offA[j] = iy0 * WW + ix0m;
        offB[j] = iy1 * WW + ix0m;
    }

    const float* ib   = img + (size_t)b * (CC * HW);
    float*       outb = out + (size_t)b * (CC * HW) + h0 * WW + w;

    // Issue all 12 gather loads before any arithmetic consumes them.
    f32x2 fa[2][CC], fb[2][CC];
#pragma unroll
    for (int c = 0; c < CC; ++c) {
        const float* p = ib + c * HW;
#pragma unroll
        for (int j = 0; j < 2; ++j) {
            __builtin_memcpy(&fa[j][c], p + offA[j], 8);
            __builtin_memcpy(&fb[j][c], p + offB[j], 8);
        }
    }

#pragma unroll
    for (int c = 0; c < CC; ++c) {
#pragma unroll
        for (int j = 0; j < 2; ++j) {
            float A  = hi[j]    ? fa[j][c].y : fa[j][c].x;
            float Cv = clipx[j] ? A          : fa[j][c].y;
            float Bv = hi[j]    ? fb[j][c].y : fb[j][c].x;
            float Dv = clipx[j] ? Bv         : fb[j][c].y;
            float v = wts[j][0] * A + wts[j][1] * Bv + wts[j][2] * Cv + wts[j][3] * Dv;
            __builtin_nontemporal_store(v, outb + c * HW + j * WW);
        }
    }
}

extern "C" void kernel_launch(void* const* d_in, const int* in_sizes, int n_in,
                              void* d_out, int out_size, void* d_ws, size_t ws_size,
                              hipStream_t stream) {
    const float* img = (const float*)d_in[0];
    const float* Htf = (const float*)d_in[1];
    float* out = (float*)d_out;

    int blocks = (BB * HH * WW) / (256 * 2);   // 16384
    warp_kernel<<<blocks, 256, 0, stream>>>(img, Htf, out);
}

// Round 7
// 39.204 us; speedup vs baseline: 2.7370x; 1.0013x over previous
//
#include <hip/hip_runtime.h>

#define BB 32
#define CC 3
#define HH 512
#define WW 512

typedef float f32x2 __attribute__((ext_vector_type(2)));

// 16384 blocks x 256 threads x 2 px/thread (vertically adjacent rows h, h+1).
// - XCD swizzle (R3/R4 win): XCD k = blockIdx.x % 8 owns 2048 logical blocks
//   = 4 whole batch images -> row reuse stays in one XCD's L2.
// - Paired 8B corner loads (R5 win): 2 gathers per row instead of 4.
// - R7 isolation experiment: REGULAR stores (NT removed) to test whether NT
//   no-allocate streaming was throttling the write path (2.5 TB/s observed)
//   or protecting the caches (FETCH 47 MB). Single-variable change vs R6.
__global__ __launch_bounds__(256) void warp_kernel(const float* __restrict__ img,
                                                   const float* __restrict__ Htf,
                                                   float* __restrict__ out) {
    const int HW = HH * WW;

    int lb  = (blockIdx.x & 7) * 2048 + (blockIdx.x >> 3);  // logical block, 0..16383
    int b   = lb >> 9;                                      // 512 blocks per batch
    int rem = lb & 511;                                     // 256 row-pairs x 2 halves
    int h0  = (rem >> 1) * 2;
    int w   = (rem & 1) * 256 + threadIdx.x;

    // b uniform across block -> scalar loads
    const float* Hp = Htf + b * 9;
    float h00 = Hp[0], h01 = Hp[1], h02 = Hp[2];
    float h10 = Hp[3], h11 = Hp[4], h12 = Hp[5];
    float h20 = Hp[6], h21 = Hp[7], h22 = Hp[8];

    float gx = -1.0f + 2.0f * (float)w / (float)(WW - 1);

    float wts[2][4];
    int   offA[2], offB[2];
    bool  clipx[2], hi[2];

#pragma unroll
    for (int j = 0; j < 2; ++j) {
        int h = h0 + j;
        float gy = -1.0f + 2.0f * (float)h / (float)(HH - 1);

        float X = h00 * gx + h01 * gy + h02;
        float Y = h10 * gx + h11 * gy + h12;
        float T = h20 * gx + h21 * gy + h22;
        float rT = 1.0f / T;
        float x = X * rT;
        float y = Y * rT;

        float px = (x + 1.0f) * (WW * 0.5f);
        float py = (y + 1.0f) * (HH * 0.5f);

        float fxf = floorf(px), fyf = floorf(py);
        float x0 = fminf(fmaxf(fxf,        0.0f), (float)(WW - 1));
        float x1 = fminf(fmaxf(fxf + 1.0f, 0.0f), (float)(WW - 1));
        float y0 = fminf(fmaxf(fyf,        0.0f), (float)(HH - 1));
        float y1 = fminf(fmaxf(fyf + 1.0f, 0.0f), (float)(HH - 1));

        wts[j][0] = (x1 - px) * (y1 - py);   // wa
        wts[j][1] = (x1 - px) * (py - y0);   // wb
        wts[j][2] = (px - x0) * (y1 - py);   // wc
        wts[j][3] = (px - x0) * (py - y0);   // wd

        int ix0 = (int)x0, ix1 = (int)x1, iy0 = (int)y0, iy1 = (int)y1;
        clipx[j] = (ix1 == ix0);
        hi[j]    = (ix0 == WW - 1);
        int ix0m = min(ix0, WW - 2);
        offA[j] = iy0 * WW + ix0m;
        offB[j] = iy1 * WW + ix0m;
    }

    const float* ib   = img + (size_t)b * (CC * HW);
    float*       outb = out + (size_t)b * (CC * HW) + h0 * WW + w;

    // Issue all 12 gather loads before any arithmetic consumes them.
    f32x2 fa[2][CC], fb[2][CC];
#pragma unroll
    for (int c = 0; c < CC; ++c) {
        const float* p = ib + c * HW;
#pragma unroll
        for (int j = 0; j < 2; ++j) {
            __builtin_memcpy(&fa[j][c], p + offA[j], 8);
            __builtin_memcpy(&fb[j][c], p + offB[j], 8);
        }
    }

#pragma unroll
    for (int c = 0; c < CC; ++c) {
#pragma unroll
        for (int j = 0; j < 2; ++j) {
            float A  = hi[j]    ? fa[j][c].y : fa[j][c].x;
            float Cv = clipx[j] ? A          : fa[j][c].y;
            float Bv = hi[j]    ? fb[j][c].y : fb[j][c].x;
            float Dv = clipx[j] ? Bv         : fb[j][c].y;
            float v = wts[j][0] * A + wts[j][1] * Bv + wts[j][2] * Cv + wts[j][3] * Dv;
            outb[c * HW + j * WW] = v;
        }
    }
}

extern "C" void kernel_launch(void* const* d_in, const int* in_sizes, int n_in,
                              void* d_out, int out_size, void* d_ws, size_t ws_size,
                              hipStream_t stream) {
    const float* img = (const float*)d_in[0];
    const float* Htf = (const float*)d_in[1];
    float* out = (float*)d_out;

    int blocks = (BB * HH * WW) / (256 * 2);   // 16384
    warp_kernel<<<blocks, 256, 0, stream>>>(img, Htf, out);
}